// Round 2
// baseline (24.291 us; speedup 1.0000x reference)
//
#include <hip/hip_runtime.h>

#define B_N 4096
#define K_N 50
#define D_N 128
#define BLOCK_T 256
#define WAVES_PER_BLOCK 4
#define SAMPLES_PER_BLOCK 2                 // 2 waves share one sample's K range
#define NBLOCKS (B_N / SAMPLES_PER_BLOCK)   // 2048 blocks -> 8192 waves = 32/CU

__global__ __launch_bounds__(BLOCK_T) void disloss_main(
    const float* __restrict__ emb_batch,   // [B, D]
    const float* __restrict__ embedding,   // [V, D]
    const float* __restrict__ attr_sim,    // [B, K]
    const int*   __restrict__ indices,     // [B, K]
    float*       __restrict__ partials)    // [NBLOCKS]
{
    const int wave = threadIdx.x >> 6;      // 0..3
    const int lane = threadIdx.x & 63;
    const int half = lane >> 5;             // 0 or 1: which k of the pair
    const int sub  = (lane & 31) * 4;       // float4 slot within the 128-f32 row
    const int s    = wave >> 1;             // sample within block (0..1)
    const int p    = wave & 1;              // which half of the K range
    const int b    = blockIdx.x * SAMPLES_PER_BLOCK + s;

    // Each half-wave covers the full 512 B row: lanes (0..31) and (32..63) read
    // the same emb_batch row, different gathered rows.
    const float4 eb = *reinterpret_cast<const float4*>(
        &emb_batch[(size_t)b * D_N + sub]);

    const int kbase  = p ? 26 : 0;
    const int npairs = p ? 12 : 13;          // 26 + 24 = 50 k's total

    int   myidx  = 0;
    float myattr = 0.0f;
    if (lane < 2 * npairs) {
        myidx  = indices[(size_t)b * K_N + kbase + lane];
        myattr = attr_sim[(size_t)b * K_N + kbase + lane];
    }

    float acc = 0.0f;
    #pragma unroll 4
    for (int it = 0; it < npairs; ++it) {
        const int   kl  = 2 * it + half;     // lane-half picks k0 or k1
        const int   idx = __shfl(myidx,  kl);
        const float a   = __shfl(myattr, kl);
        const float4 g = *reinterpret_cast<const float4*>(
            &embedding[(size_t)idx * D_N + sub]);
        const float dx = g.x - eb.x;
        const float dy = g.y - eb.y;
        const float dz = g.z - eb.z;
        const float dw = g.w - eb.w;
        acc += a * (dx * dx + dy * dy + dz * dz + dw * dw);
    }

    // Wave reduction (64 lanes)
    #pragma unroll
    for (int off = 32; off > 0; off >>= 1)
        acc += __shfl_down(acc, off);

    __shared__ float smem[WAVES_PER_BLOCK];
    if (lane == 0) smem[wave] = acc;
    __syncthreads();
    if (threadIdx.x == 0)
        partials[blockIdx.x] = smem[0] + smem[1] + smem[2] + smem[3];
}

__global__ __launch_bounds__(BLOCK_T) void disloss_reduce(
    const float* __restrict__ partials,
    float*       __restrict__ out)
{
    float acc = 0.0f;
    #pragma unroll
    for (int i = threadIdx.x; i < NBLOCKS; i += BLOCK_T)
        acc += partials[i];

    #pragma unroll
    for (int off = 32; off > 0; off >>= 1)
        acc += __shfl_down(acc, off);

    __shared__ float smem[WAVES_PER_BLOCK];
    const int wave = threadIdx.x >> 6;
    const int lane = threadIdx.x & 63;
    if (lane == 0) smem[wave] = acc;
    __syncthreads();
    if (threadIdx.x == 0)
        out[0] = (smem[0] + smem[1] + smem[2] + smem[3]) / (float)B_N;
}

extern "C" void kernel_launch(void* const* d_in, const int* in_sizes, int n_in,
                              void* d_out, int out_size, void* d_ws, size_t ws_size,
                              hipStream_t stream) {
    const float* emb_batch = (const float*)d_in[0];   // [B, D]
    const float* embedding = (const float*)d_in[1];   // [V, D]
    const float* attr_sim  = (const float*)d_in[2];   // [B, K]
    const int*   indices   = (const int*)d_in[3];     // [B, K]
    // d_in[4] = beta (unused by the reference computation)

    float* out      = (float*)d_out;
    float* partials = (float*)d_ws;                   // NBLOCKS floats (8 KB)

    disloss_main<<<NBLOCKS, BLOCK_T, 0, stream>>>(emb_batch, embedding, attr_sim,
                                                  indices, partials);
    disloss_reduce<<<1, BLOCK_T, 0, stream>>>(partials, out);
}